// Round 3
// baseline (269.987 us; speedup 1.0000x reference)
//
#include <hip/hip_runtime.h>

#define DHW    65536
#define NCH    256
#define NNODE  7
#define NHID   128
#define NBATCH 2
#define CCH    64      // channels per chunk
#define NCC    4       // chunks (NCC*CCH == NCH)
#define PTILE  1024    // points per block tile

__device__ inline float4 f4fma(float4 v, float w, float4 a) {
    a.x = fmaf(v.x, w, a.x); a.y = fmaf(v.y, w, a.y);
    a.z = fmaf(v.z, w, a.z); a.w = fmaf(v.w, w, a.w);
    return a;
}
__device__ inline float4 f4max(float4 a, float4 b) {
    return make_float4(fmaxf(a.x,b.x), fmaxf(a.y,b.y), fmaxf(a.z,b.z), fmaxf(a.w,b.w));
}
__device__ inline float4 f4expsub(float4 a, float4 m) {
    return make_float4(__expf(a.x-m.x), __expf(a.y-m.y), __expf(a.z-m.z), __expf(a.w-m.w));
}
__device__ inline float4 f4add(float4 a, float4 b) {
    return make_float4(a.x+b.x, a.y+b.y, a.z+b.z, a.w+b.w);
}
__device__ inline float4 f4mul(float4 a, float4 b) {
    return make_float4(a.x*b.x, a.y*b.y, a.z*b.z, a.w*b.w);
}
__device__ inline float4 f4relu(float4 a) {
    return make_float4(fmaxf(a.x,0.f), fmaxf(a.y,0.f), fmaxf(a.z,0.f), fmaxf(a.w,0.f));
}

// ---------------------------------------------------------------------------
// Prep: nwt[b][c][8] = new_weight^T padded; n2g[b][8]; w1p[c][8] padded.
// ---------------------------------------------------------------------------
__global__ void prep_kernel(const float* __restrict__ inp,
                            const float* __restrict__ nfh,
                            const float* __restrict__ weight,
                            const float* __restrict__ w1,
                            float* __restrict__ nwt,
                            float* __restrict__ n2g,
                            float* __restrict__ w1p)
{
    const int bn = blockIdx.x;
    const int b  = bn / NNODE;
    const int n  = bn % NNODE;
    const int t  = threadIdx.x;
    const float* ih = inp + (b * NNODE + n) * NHID;

    float acc = 0.f;
    #pragma unroll 8
    for (int h = 0; h < NHID; ++h)
        acc = fmaf(ih[h], weight[h * NCH + t], acc);
    nwt[(b * NCH + t) * 8 + n] = acc;

    if (bn == 0) {
        #pragma unroll
        for (int k = 0; k < NNODE; ++k) w1p[t * 8 + k] = w1[t * NNODE + k];
        w1p[t * 8 + 7] = 0.f;
    }

    __shared__ float red[NHID];
    if (t < NHID) red[t] = ih[t] * nfh[t];
    __syncthreads();
    for (int s = NHID / 2; s > 0; s >>= 1) {
        if (t < s) red[t] += red[t + s];
        __syncthreads();
    }
    if (t == 0) n2g[b * 8 + n] = red[0];
}

// ---------------------------------------------------------------------------
// K1: partial scores. blk = ((b*NCC)+cc)*64 + pc  (pc fastest for streaming).
// Thread t -> float4 of points p0..p0+3. 64-channel register accumulation.
// Reads rf in 4 KiB contiguous runs/block/channel; writes partials contiguous.
// ---------------------------------------------------------------------------
__global__ __launch_bounds__(256, 2)
void score_kernel(const float* __restrict__ rf,    // [2][256][65536]
                  const float* __restrict__ w1p,   // [256][8]
                  float* __restrict__ partial)     // [2][NCC][8][65536]
{
    const int blk = blockIdx.x;
    const int pc  = blk & 63;
    const int cc  = (blk >> 6) & (NCC - 1);
    const int b   = blk >> 8;
    const int t   = threadIdx.x;
    const int i4  = pc * 256 + t;            // float4 index within channel plane
    const int c0  = cc * CCH;

    const float4* rp = (const float4*)rf + (((size_t)(b * NCH + c0)) << 14) + i4;
    const float4* wq = (const float4*)w1p + (c0 << 1);

    float4 a0 = {0,0,0,0}, a1 = {0,0,0,0}, a2 = {0,0,0,0}, a3 = {0,0,0,0};
    float4 a4 = {0,0,0,0}, a5 = {0,0,0,0}, a6 = {0,0,0,0};

    #pragma unroll 8
    for (int ci = 0; ci < CCH; ++ci) {
        float4 v  = rp[(size_t)ci << 14];
        float4 wa = wq[ci * 2];      // uniform -> scalar loads
        float4 wb = wq[ci * 2 + 1];
        a0 = f4fma(v, wa.x, a0);
        a1 = f4fma(v, wa.y, a1);
        a2 = f4fma(v, wa.z, a2);
        a3 = f4fma(v, wa.w, a3);
        a4 = f4fma(v, wb.x, a4);
        a5 = f4fma(v, wb.y, a5);
        a6 = f4fma(v, wb.z, a6);
    }

    float4* pp = (float4*)partial + (((b * NCC + cc) * 8) << 14) + i4;
    pp[0 << 14] = a0;  pp[1 << 14] = a1;  pp[2 << 14] = a2;  pp[3 << 14] = a3;
    pp[4 << 14] = a4;  pp[5 << 14] = a5;  pp[6 << 14] = a6;
}

// ---------------------------------------------------------------------------
// K2: combine partials + n2, softmax over 7 nodes, write attn[b][n][p] planes.
// Grid: 128 blocks x 256 threads, thread -> one float4 (4 points).
// ---------------------------------------------------------------------------
__global__ void softmax_kernel(const float* __restrict__ partial,
                               const float* __restrict__ n2g,
                               float* __restrict__ attn)   // [2][8][65536]
{
    const int g  = blockIdx.x * 256 + threadIdx.x;   // [0, 32768)
    const int b  = g >> 14;
    const int i4 = g & 16383;

    const float4* pp = (const float4*)partial + (((size_t)b * NCC * 8) << 14) + i4;
    const float*  n2 = n2g + b * 8;

    float4 s[NNODE];
    #pragma unroll
    for (int n = 0; n < NNODE; ++n) {
        float4 acc = make_float4(n2[n], n2[n], n2[n], n2[n]);
        #pragma unroll
        for (int cc = 0; cc < NCC; ++cc)
            acc = f4add(acc, pp[(size_t)((cc * 8 + n)) << 14]);
        s[n] = acc;
    }
    float4 m = s[0];
    #pragma unroll
    for (int n = 1; n < NNODE; ++n) m = f4max(m, s[n]);
    float4 e[NNODE];
    float4 sum = {0,0,0,0};
    #pragma unroll
    for (int n = 0; n < NNODE; ++n) { e[n] = f4expsub(s[n], m); sum = f4add(sum, e[n]); }
    float4 inv = make_float4(1.f/sum.x, 1.f/sum.y, 1.f/sum.z, 1.f/sum.w);

    float4* ap = (float4*)attn + (((size_t)b * 8) << 14) + i4;
    #pragma unroll
    for (int n = 0; n < NNODE; ++n) ap[(size_t)n << 14] = f4mul(e[n], inv);
}

// ---------------------------------------------------------------------------
// K3: output. Same block mapping as K1. Thread loads 7 attn float4s, then
// writes 64 channels x float4, fully contiguous runs. nwt via scalar loads.
// ---------------------------------------------------------------------------
__global__ __launch_bounds__(256, 2)
void out_kernel(const float* __restrict__ attn,   // [2][8][65536]
                const float* __restrict__ nwt,    // [2][256][8]
                float* __restrict__ out)          // [2][256][65536]
{
    const int blk = blockIdx.x;
    const int pc  = blk & 63;
    const int cc  = (blk >> 6) & (NCC - 1);
    const int b   = blk >> 8;
    const int t   = threadIdx.x;
    const int i4  = pc * 256 + t;
    const int c0  = cc * CCH;

    const float4* ap = (const float4*)attn + (((size_t)b * 8) << 14) + i4;
    float4 a[NNODE];
    #pragma unroll
    for (int n = 0; n < NNODE; ++n) a[n] = ap[(size_t)n << 14];

    const float4* nq = (const float4*)nwt + ((b * NCH + c0) << 1);
    float4* op = (float4*)out + (((size_t)(b * NCH + c0)) << 14) + i4;

    #pragma unroll 8
    for (int ci = 0; ci < CCH; ++ci) {
        float4 na = nq[ci * 2];      // uniform -> scalar loads
        float4 nb = nq[ci * 2 + 1];
        float4 o = {0,0,0,0};
        o = f4fma(a[0], na.x, o);
        o = f4fma(a[1], na.y, o);
        o = f4fma(a[2], na.z, o);
        o = f4fma(a[3], na.w, o);
        o = f4fma(a[4], nb.x, o);
        o = f4fma(a[5], nb.y, o);
        o = f4fma(a[6], nb.z, o);
        op[(size_t)ci << 14] = f4relu(o);
    }
}

extern "C" void kernel_launch(void* const* d_in, const int* in_sizes, int n_in,
                              void* d_out, int out_size, void* d_ws, size_t ws_size,
                              hipStream_t stream) {
    const float* inp = (const float*)d_in[0];   // (1,2,7,128)
    const float* rf  = (const float*)d_in[1];   // (2,256,16,64,64)
    const float* w1  = (const float*)d_in[2];   // (256,7)
    const float* nfh = (const float*)d_in[3];   // (128,1)
    const float* wgt = (const float*)d_in[4];   // (128,256)
    float* out = (float*)d_out;

    float* partial = (float*)d_ws;                        // [2][4][8][65536] = 16 MiB
    float* attn    = partial + (size_t)NBATCH*NCC*8*DHW;  // [2][8][65536]    = 4 MiB
    float* nwt     = attn    + (size_t)NBATCH*8*DHW;      // [2][256][8]
    float* n2g     = nwt     + NBATCH*NCH*8;              // [2][8]
    float* w1p     = n2g     + NBATCH*8;                  // [256][8]

    prep_kernel<<<NBATCH * NNODE, 256, 0, stream>>>(inp, nfh, wgt, w1, nwt, n2g, w1p);
    score_kernel<<<NBATCH * NCC * 64, 256, 0, stream>>>(rf, w1p, partial);
    softmax_kernel<<<128, 256, 0, stream>>>(partial, n2g, attn);
    out_kernel<<<NBATCH * NCC * 64, 256, 0, stream>>>(attn, nwt, out);
}

// Round 5
// 245.305 us; speedup vs baseline: 1.1006x; 1.1006x over previous
//
#include <hip/hip_runtime.h>

#define DHW    65536
#define NCH    256
#define NNODE  7
#define NHID   128
#define NBATCH 2

typedef float vf4 __attribute__((ext_vector_type(4)));

__device__ inline float4 f4fma(float4 v, float w, float4 a) {
    a.x = fmaf(v.x, w, a.x); a.y = fmaf(v.y, w, a.y);
    a.z = fmaf(v.z, w, a.z); a.w = fmaf(v.w, w, a.w);
    return a;
}

// ---------------------------------------------------------------------------
// Prep: nwt[b][c][8] = new_weight^T padded; n2g[b][8]; w1p[c][8] padded.
// ---------------------------------------------------------------------------
__global__ void prep_kernel(const float* __restrict__ inp,
                            const float* __restrict__ nfh,
                            const float* __restrict__ weight,
                            const float* __restrict__ w1,
                            float* __restrict__ nwt,
                            float* __restrict__ n2g,
                            float* __restrict__ w1p)
{
    const int bn = blockIdx.x;
    const int b  = bn / NNODE;
    const int n  = bn % NNODE;
    const int t  = threadIdx.x;
    const float* ih = inp + (b * NNODE + n) * NHID;

    float acc = 0.f;
    #pragma unroll 8
    for (int h = 0; h < NHID; ++h)
        acc = fmaf(ih[h], weight[h * NCH + t], acc);
    nwt[(b * NCH + t) * 8 + n] = acc;

    if (bn == 0) {
        #pragma unroll
        for (int k = 0; k < NNODE; ++k) w1p[t * 8 + k] = w1[t * NNODE + k];
        w1p[t * 8 + 7] = 0.f;
    }

    __shared__ float red[NHID];
    if (t < NHID) red[t] = ih[t] * nfh[t];
    __syncthreads();
    for (int s = NHID / 2; s > 0; s >>= 1) {
        if (t < s) red[t] += red[t + s];
        __syncthreads();
    }
    if (t == 0) n2g[b * 8 + n] = red[0];
}

// ---------------------------------------------------------------------------
// Main: block = 256 threads (4 waves) handling 256 points as float4/thread.
// Wave w owns channels [64w, 64w+64). Phase 1: per-wave partial scores with
// 1 KiB contiguous nontemporal float4 loads; LDS cross-wave reduce; softmax
// (redundant per wave); Phase 2: each wave streams its 64 output channels
// with nontemporal float4 stores. Total HBM demand = 128 MiB in + 128 MiB out.
// Grid: 512 blocks -> 2048 waves -> 8 waves/CU.
// ---------------------------------------------------------------------------
__global__ __launch_bounds__(256, 2)
void main_kernel(const float* __restrict__ rf,    // [2][256][65536]
                 const float* __restrict__ w1p,   // [256][8]
                 const float* __restrict__ nwt,   // [2][256][8]
                 const float* __restrict__ n2g,   // [2][8]
                 float* __restrict__ out)         // [2][256][65536]
{
    __shared__ float4 red[NNODE][4][64];   // 28 KiB

    const int t    = threadIdx.x;
    const int lane = t & 63;
    const int wv   = __builtin_amdgcn_readfirstlane(t >> 6);  // 0..3 uniform
    const int blk  = blockIdx.x;            // 0..511
    const int b    = blk >> 8;
    const int i4   = ((blk & 255) << 6) + lane;   // float4 idx in plane [0,16384)
    const int c0   = wv << 6;

    // ---- Phase 1: partial scores over this wave's 64 channels -----------
    const vf4* rp = (const vf4*)rf + (((size_t)(b * NCH + c0)) << 14) + i4;
    const float4* wq = (const float4*)w1p + (c0 << 1);

    float4 a0 = {0,0,0,0}, a1 = {0,0,0,0}, a2 = {0,0,0,0}, a3 = {0,0,0,0};
    float4 a4 = {0,0,0,0}, a5 = {0,0,0,0}, a6 = {0,0,0,0};

    #pragma unroll 8
    for (int ci = 0; ci < 64; ++ci) {
        vf4 vv = __builtin_nontemporal_load(&rp[(size_t)ci << 14]);
        float4 v = make_float4(vv.x, vv.y, vv.z, vv.w);
        float4 wa = wq[ci * 2];       // uniform -> scalar loads
        float4 wb = wq[ci * 2 + 1];
        a0 = f4fma(v, wa.x, a0);
        a1 = f4fma(v, wa.y, a1);
        a2 = f4fma(v, wa.z, a2);
        a3 = f4fma(v, wa.w, a3);
        a4 = f4fma(v, wb.x, a4);
        a5 = f4fma(v, wb.y, a5);
        a6 = f4fma(v, wb.z, a6);
    }

    red[0][wv][lane] = a0;  red[1][wv][lane] = a1;  red[2][wv][lane] = a2;
    red[3][wv][lane] = a3;  red[4][wv][lane] = a4;  red[5][wv][lane] = a5;
    red[6][wv][lane] = a6;
    __syncthreads();

    // ---- Cross-wave reduce + softmax (all waves need full attn) ---------
    const float* n2 = n2g + b * 8;   // uniform -> scalar loads
    float4 s[NNODE];
    #pragma unroll
    for (int n = 0; n < NNODE; ++n) {
        float4 r = red[n][0][lane];
        #pragma unroll
        for (int w = 1; w < 4; ++w) {
            float4 q = red[n][w][lane];
            r.x += q.x; r.y += q.y; r.z += q.z; r.w += q.w;
        }
        r.x += n2[n]; r.y += n2[n]; r.z += n2[n]; r.w += n2[n];
        s[n] = r;
    }
    float4 m = s[0];
    #pragma unroll
    for (int n = 1; n < NNODE; ++n) {
        m.x = fmaxf(m.x, s[n].x); m.y = fmaxf(m.y, s[n].y);
        m.z = fmaxf(m.z, s[n].z); m.w = fmaxf(m.w, s[n].w);
    }
    float4 sum = {0,0,0,0};
    float4 e[NNODE];
    #pragma unroll
    for (int n = 0; n < NNODE; ++n) {
        e[n].x = __expf(s[n].x - m.x); e[n].y = __expf(s[n].y - m.y);
        e[n].z = __expf(s[n].z - m.z); e[n].w = __expf(s[n].w - m.w);
        sum.x += e[n].x; sum.y += e[n].y; sum.z += e[n].z; sum.w += e[n].w;
    }
    float4 inv = make_float4(1.f/sum.x, 1.f/sum.y, 1.f/sum.z, 1.f/sum.w);
    #pragma unroll
    for (int n = 0; n < NNODE; ++n) {
        e[n].x *= inv.x; e[n].y *= inv.y; e[n].z *= inv.z; e[n].w *= inv.w;
    }

    // ---- Phase 2: this wave's 64 output channels ------------------------
    const float4* nq = (const float4*)nwt + ((b * NCH + c0) << 1);  // uniform
    vf4* op = (vf4*)out + (((size_t)(b * NCH + c0)) << 14) + i4;
    #pragma unroll 8
    for (int ci = 0; ci < 64; ++ci) {
        float4 na = nq[ci * 2];       // uniform -> scalar loads
        float4 nb = nq[ci * 2 + 1];
        float4 o = {0,0,0,0};
        o = f4fma(e[0], na.x, o);
        o = f4fma(e[1], na.y, o);
        o = f4fma(e[2], na.z, o);
        o = f4fma(e[3], na.w, o);
        o = f4fma(e[4], nb.x, o);
        o = f4fma(e[5], nb.y, o);
        o = f4fma(e[6], nb.z, o);
        vf4 ov;
        ov.x = fmaxf(o.x, 0.f); ov.y = fmaxf(o.y, 0.f);
        ov.z = fmaxf(o.z, 0.f); ov.w = fmaxf(o.w, 0.f);
        __builtin_nontemporal_store(ov, &op[(size_t)ci << 14]);
    }
}

extern "C" void kernel_launch(void* const* d_in, const int* in_sizes, int n_in,
                              void* d_out, int out_size, void* d_ws, size_t ws_size,
                              hipStream_t stream) {
    const float* inp = (const float*)d_in[0];   // (1,2,7,128)
    const float* rf  = (const float*)d_in[1];   // (2,256,16,64,64)
    const float* w1  = (const float*)d_in[2];   // (256,7)
    const float* nfh = (const float*)d_in[3];   // (128,1)
    const float* wgt = (const float*)d_in[4];   // (128,256)
    float* out = (float*)d_out;

    float* nwt = (float*)d_ws;                  // [2][256][8]
    float* n2g = nwt + NBATCH * NCH * 8;        // [2][8]
    float* w1p = n2g + NBATCH * 8;              // [256][8]

    prep_kernel<<<NBATCH * NNODE, 256, 0, stream>>>(inp, nfh, wgt, w1, nwt, n2g, w1p);
    main_kernel<<<NBATCH * 256, 256, 0, stream>>>(rf, w1p, nwt, n2g, out);
}